// Round 2
// baseline (427.329 us; speedup 1.0000x reference)
//
#include <hip/hip_runtime.h>
#include <math.h>

#define NH    24
#define DM    512
#define DP    128
#define EMAX  2048
#define DIN   3584   // 512 + 24*128
#define B     64

// ws layout (floats):
//   x_T   [DIN][B]        = 3584*64   = 229376 f  (917504 B)
//   part  [8][B][DM]      = 8*64*512  = 262144 f  (1 MB)
//   hbuf  [B][DM]         = 64*512    = 32768 f   (128 KB)

// ---------------------------------------------------------------------------
// K1: per-(b,h) bin mean of episode_ctx (contiguous slice), project through
//     W_pool, write x_T[512 + h*128 + k][b]. Block h==24 copies day_embed
//     into x_T[0:512][b].
// grid (25, 64), block 256
// ---------------------------------------------------------------------------
__global__ void binpool_kernel(const float* __restrict__ day_embed,
                               const float* __restrict__ episode_ctx,
                               const int* __restrict__ n_episodes,
                               const float* __restrict__ W_pool,
                               const float* __restrict__ b_pool,
                               float* __restrict__ x_T) {
    const int h = blockIdx.x;   // 0..24 (24 == day_embed copy)
    const int b = blockIdx.y;
    const int t = threadIdx.x;  // 0..255

    if (h == NH) {
        for (int i = t; i < DM; i += 256)
            x_T[(size_t)i * B + b] = day_embed[b * DM + i];
        return;
    }

    const int n  = n_episodes[b];
    int bs = n / NH; if (bs < 1) bs = 1;
    const int lo = h * bs;
    int hi = lo + bs; if (hi > n) hi = n;
    int count = hi - lo; if (count < 0) count = 0;

    __shared__ float sh_mean[DM];

    // thread t accumulates dims (2t, 2t+1) over episodes [lo, hi)
    float a0 = 0.f, a1 = 0.f;
    const float2* base = (const float2*)episode_ctx
                       + (size_t)b * EMAX * (DM / 2) + t;
    #pragma unroll 4
    for (int e = lo; e < hi; ++e) {
        float2 v = base[(size_t)e * (DM / 2)];
        a0 += v.x;
        a1 += v.y;
    }
    const float inv = (count > 0) ? (1.0f / (float)count) : 0.0f;
    sh_mean[2 * t]     = a0 * inv;
    sh_mean[2 * t + 1] = a1 * inv;
    __syncthreads();

    // projection: thread t<64 computes outputs k = 2t, 2t+1
    if (t < 64) {
        float c0 = 0.f, c1 = 0.f;
        const float2* wp = (const float2*)W_pool + t;   // pair (2t,2t+1) of row d
        #pragma unroll 4
        for (int d = 0; d < DM; ++d) {
            float m = sh_mean[d];
            float2 w = wp[(size_t)d * (DP / 2)];
            c0 += m * w.x;
            c1 += m * w.y;
        }
        const int row = DM + h * DP + 2 * t;
        if (count > 0) {
            x_T[(size_t)row * B + b]       = c0 + b_pool[2 * t];
            x_T[(size_t)(row + 1) * B + b] = c1 + b_pool[2 * t + 1];
        } else {
            x_T[(size_t)row * B + b]       = 0.f;
            x_T[(size_t)(row + 1) * B + b] = 0.f;
        }
    }
}

// ---------------------------------------------------------------------------
// K2: partial GEMM  part[s] += X^T slab . W1 slab
// grid (32, 8): blockIdx.x = 16-col chunk, blockIdx.y = K slab (448 rows).
// block 256 = 4 waves; wave w handles k in [448*s + 112*w, +112).
// lane = batch row (coalesced X^T reads); W1 row chunk is wave-uniform
// (scalar loads). 16 fp32 accumulators per lane.
// ---------------------------------------------------------------------------
__global__ void mlp1_kernel(const float* __restrict__ x_T,
                            const float* __restrict__ W1,
                            float* __restrict__ part) {
    const int c = blockIdx.x;          // 0..31 -> cols [16c, 16c+16)
    const int s = blockIdx.y;          // 0..7  -> k in [448s, 448s+448)
    const int t = threadIdx.x;
    const int w = t >> 6;              // wave 0..3
    const int lane = t & 63;           // batch row

    float acc[16];
    #pragma unroll
    for (int j = 0; j < 16; ++j) acc[j] = 0.f;

    const int k0 = 448 * s + 112 * w;
    const float* wbase = W1 + (size_t)k0 * DM + 16 * c;
    const float* xbase = x_T + (size_t)k0 * B + lane;

    #pragma unroll 4
    for (int ki = 0; ki < 112; ++ki) {
        float xv = xbase[ki * B];
        const float* wrow = wbase + (size_t)ki * DM;
        #pragma unroll
        for (int j = 0; j < 16; ++j)
            acc[j] += xv * wrow[j];
    }

    __shared__ float red[4][64][17];   // pad 17: avoid 32-way bank conflict
    #pragma unroll
    for (int j = 0; j < 16; ++j)
        red[w][lane][j] = acc[j];
    __syncthreads();

    // 64 rows x 16 cols = 1024 outputs, 256 threads -> 4 each
    for (int idx = t; idx < 1024; idx += 256) {
        const int row = idx >> 4;
        const int j   = idx & 15;
        float v = red[0][row][j] + red[1][row][j] + red[2][row][j] + red[3][row][j];
        part[(size_t)s * (B * DM) + (size_t)row * DM + 16 * c + j] = v;
    }
}

// ---------------------------------------------------------------------------
// K3: hbuf = gelu(sum_s part[s] + b1)   exact erf GELU
// grid 128, block 256  (64*512 = 32768 outputs)
// ---------------------------------------------------------------------------
__global__ void epilogue_kernel(const float* __restrict__ part,
                                const float* __restrict__ b1,
                                float* __restrict__ hbuf) {
    const int idx = blockIdx.x * 256 + threadIdx.x;   // < 32768
    const int col = idx & (DM - 1);
    float v = 0.f;
    #pragma unroll
    for (int s = 0; s < 8; ++s)
        v += part[(size_t)s * (B * DM) + idx];
    v += b1[col];
    v = 0.5f * v * (1.0f + erff(v * 0.70710678118654752f));
    hbuf[idx] = v;
}

// ---------------------------------------------------------------------------
// K4: out = hbuf @ W2 + b2    out fp32 [64,2]
// grid 64, block 64 (one wave per row)
// ---------------------------------------------------------------------------
__global__ void mlp2_kernel(const float* __restrict__ hbuf,
                            const float* __restrict__ W2,
                            const float* __restrict__ b2,
                            float* __restrict__ out) {
    const int b = blockIdx.x;
    const int t = threadIdx.x;   // 0..63
    float a0 = 0.f, a1 = 0.f;
    #pragma unroll
    for (int i = t; i < DM; i += 64) {
        float hv = hbuf[(size_t)b * DM + i];
        float2 w = ((const float2*)W2)[i];
        a0 += hv * w.x;
        a1 += hv * w.y;
    }
    #pragma unroll
    for (int off = 32; off > 0; off >>= 1) {
        a0 += __shfl_down(a0, off);
        a1 += __shfl_down(a1, off);
    }
    if (t == 0) {
        out[b * 2]     = a0 + b2[0];
        out[b * 2 + 1] = a1 + b2[1];
    }
}

extern "C" void kernel_launch(void* const* d_in, const int* in_sizes, int n_in,
                              void* d_out, int out_size, void* d_ws, size_t ws_size,
                              hipStream_t stream) {
    const float* day_embed   = (const float*)d_in[0];
    const float* episode_ctx = (const float*)d_in[1];
    const int*   n_episodes  = (const int*)d_in[2];
    const float* W_pool      = (const float*)d_in[3];
    const float* b_pool      = (const float*)d_in[4];
    const float* W1          = (const float*)d_in[5];
    const float* b1          = (const float*)d_in[6];
    const float* W2          = (const float*)d_in[7];
    const float* b2          = (const float*)d_in[8];
    float* out = (float*)d_out;

    float* x_T  = (float*)d_ws;                 // [3584][64]
    float* part = x_T + (size_t)DIN * B;        // [8][64][512]
    float* hbuf = part + (size_t)8 * B * DM;    // [64][512]

    dim3 gA(NH + 1, B);
    binpool_kernel<<<gA, 256, 0, stream>>>(day_embed, episode_ctx, n_episodes,
                                           W_pool, b_pool, x_T);
    dim3 gB(32, 8);
    mlp1_kernel<<<gB, 256, 0, stream>>>(x_T, W1, part);

    epilogue_kernel<<<128, 256, 0, stream>>>(part, b1, hbuf);

    mlp2_kernel<<<64, 64, 0, stream>>>(hbuf, W2, b2, out);
}

// Round 3
// 423.974 us; speedup vs baseline: 1.0079x; 1.0079x over previous
//
#include <hip/hip_runtime.h>
#include <math.h>

#define NH    24
#define DM    512
#define DP    128
#define EMAX  2048
#define DIN   3584   // 512 + 24*128
#define B     64

// ws layout (floats):
//   x_T   [DIN][B]   = 229376 f
//   part  [8][B][DM] = 262144 f

// ---------------------------------------------------------------------------
// K1: per-(b,h) bin mean of episode_ctx (contiguous slice), project through
//     W_pool, write x_T[512 + h*128 + k][b]. Block h==24 copies day_embed.
// grid (25, 64), block 256
// Mean phase: float4 loads, thread t = (ep_parity = t>>7, dim-quad p = t&127);
// 2 episodes (4 KB) in flight per loop iteration.
// ---------------------------------------------------------------------------
__global__ void binpool_kernel(const float* __restrict__ day_embed,
                               const float* __restrict__ episode_ctx,
                               const int* __restrict__ n_episodes,
                               const float* __restrict__ W_pool,
                               const float* __restrict__ b_pool,
                               float* __restrict__ x_T) {
    const int h = blockIdx.x;   // 0..24 (24 == day_embed copy)
    const int b = blockIdx.y;
    const int t = threadIdx.x;  // 0..255

    if (h == NH) {
        for (int i = t; i < DM; i += 256)
            x_T[(size_t)i * B + b] = day_embed[b * DM + i];
        return;
    }

    const int n  = n_episodes[b];
    int bs = n / NH; if (bs < 1) bs = 1;
    const int lo = h * bs;
    int hi = lo + bs; if (hi > n) hi = n;
    int count = hi - lo; if (count < 0) count = 0;

    __shared__ float4 sh4[256];
    __shared__ float  sh_mean[DM];

    const int p  = t & 127;     // dim quad: dims 4p..4p+3
    const int eo = t >> 7;      // episode parity

    float4 a = make_float4(0.f, 0.f, 0.f, 0.f);
    const float4* base = (const float4*)episode_ctx
                       + (size_t)b * EMAX * (DM / 4) + p;
    #pragma unroll 2
    for (int e = lo + eo; e < hi; e += 2) {
        float4 v = base[(size_t)e * (DM / 4)];
        a.x += v.x; a.y += v.y; a.z += v.z; a.w += v.w;
    }
    sh4[t] = a;
    __syncthreads();

    if (t < 128) {
        const float inv = (count > 0) ? (1.0f / (float)count) : 0.0f;
        float4 u = sh4[t], v = sh4[t + 128];
        sh_mean[4 * t]     = (u.x + v.x) * inv;
        sh_mean[4 * t + 1] = (u.y + v.y) * inv;
        sh_mean[4 * t + 2] = (u.z + v.z) * inv;
        sh_mean[4 * t + 3] = (u.w + v.w) * inv;
    }
    __syncthreads();

    // projection: thread t<64 computes outputs k = 2t, 2t+1
    if (t < 64) {
        float c0 = 0.f, c1 = 0.f;
        const float2* wp = (const float2*)W_pool + t;
        #pragma unroll 4
        for (int d = 0; d < DM; ++d) {
            float m = sh_mean[d];
            float2 w = wp[(size_t)d * (DP / 2)];
            c0 += m * w.x;
            c1 += m * w.y;
        }
        const int row = DM + h * DP + 2 * t;
        if (count > 0) {
            x_T[(size_t)row * B + b]       = c0 + b_pool[2 * t];
            x_T[(size_t)(row + 1) * B + b] = c1 + b_pool[2 * t + 1];
        } else {
            x_T[(size_t)row * B + b]       = 0.f;
            x_T[(size_t)(row + 1) * B + b] = 0.f;
        }
    }
}

// ---------------------------------------------------------------------------
// K2: partial GEMM  part[s] = X^T slab . W1 slab
// grid (32, 8): c = 16-col chunk, s = K slab (448 rows). block 256 = 4 waves;
// wave w: k in [448s + 112w, +112). lane = batch row (coalesced x_T reads);
// W1 chunk is wave-uniform, float4 loads.
// ---------------------------------------------------------------------------
__global__ void mlp1_kernel(const float* __restrict__ x_T,
                            const float* __restrict__ W1,
                            float* __restrict__ part) {
    const int c = blockIdx.x;
    const int s = blockIdx.y;
    const int t = threadIdx.x;
    const int w = t >> 6;
    const int lane = t & 63;

    float acc[16];
    #pragma unroll
    for (int j = 0; j < 16; ++j) acc[j] = 0.f;

    const int k0 = 448 * s + 112 * w;
    const float4* wbase = (const float4*)(W1 + (size_t)k0 * DM + 16 * c);
    const float* xbase = x_T + (size_t)k0 * B + lane;

    #pragma unroll 4
    for (int ki = 0; ki < 112; ++ki) {
        float xv = xbase[ki * B];
        const float4* wrow = wbase + (size_t)ki * (DM / 4);
        #pragma unroll
        for (int q = 0; q < 4; ++q) {
            float4 wv = wrow[q];
            acc[4 * q]     += xv * wv.x;
            acc[4 * q + 1] += xv * wv.y;
            acc[4 * q + 2] += xv * wv.z;
            acc[4 * q + 3] += xv * wv.w;
        }
    }

    __shared__ float red[4][64][17];
    #pragma unroll
    for (int j = 0; j < 16; ++j)
        red[w][lane][j] = acc[j];
    __syncthreads();

    for (int idx = t; idx < 1024; idx += 256) {
        const int row = idx >> 4;
        const int j   = idx & 15;
        float v = red[0][row][j] + red[1][row][j] + red[2][row][j] + red[3][row][j];
        part[(size_t)s * (B * DM) + (size_t)row * DM + 16 * c + j] = v;
    }
}

// ---------------------------------------------------------------------------
// K3: per-b: h = gelu(sum_s part[s][b] + b1); out[b] = h @ W2 + b2
// grid 64, block 256
// ---------------------------------------------------------------------------
__global__ void tail_kernel(const float* __restrict__ part,
                            const float* __restrict__ b1,
                            const float* __restrict__ W2,
                            const float* __restrict__ b2,
                            float* __restrict__ out) {
    const int b = blockIdx.x;
    const int t = threadIdx.x;

    __shared__ float sh_h[DM];

    #pragma unroll
    for (int rep = 0; rep < 2; ++rep) {
        const int col = t + rep * 256;
        float v = 0.f;
        #pragma unroll
        for (int s = 0; s < 8; ++s)
            v += part[(size_t)s * (B * DM) + (size_t)b * DM + col];
        v += b1[col];
        sh_h[col] = 0.5f * v * (1.0f + erff(v * 0.70710678118654752f));
    }
    __syncthreads();

    if (t < 64) {
        float a0 = 0.f, a1 = 0.f;
        #pragma unroll
        for (int i = t; i < DM; i += 64) {
            float hv = sh_h[i];
            float2 w = ((const float2*)W2)[i];
            a0 += hv * w.x;
            a1 += hv * w.y;
        }
        #pragma unroll
        for (int off = 32; off > 0; off >>= 1) {
            a0 += __shfl_down(a0, off);
            a1 += __shfl_down(a1, off);
        }
        if (t == 0) {
            out[b * 2]     = a0 + b2[0];
            out[b * 2 + 1] = a1 + b2[1];
        }
    }
}

extern "C" void kernel_launch(void* const* d_in, const int* in_sizes, int n_in,
                              void* d_out, int out_size, void* d_ws, size_t ws_size,
                              hipStream_t stream) {
    const float* day_embed   = (const float*)d_in[0];
    const float* episode_ctx = (const float*)d_in[1];
    const int*   n_episodes  = (const int*)d_in[2];
    const float* W_pool      = (const float*)d_in[3];
    const float* b_pool      = (const float*)d_in[4];
    const float* W1          = (const float*)d_in[5];
    const float* b1          = (const float*)d_in[6];
    const float* W2          = (const float*)d_in[7];
    const float* b2          = (const float*)d_in[8];
    float* out = (float*)d_out;

    float* x_T  = (float*)d_ws;              // [3584][64]
    float* part = x_T + (size_t)DIN * B;     // [8][64][512]

    dim3 gA(NH + 1, B);
    binpool_kernel<<<gA, 256, 0, stream>>>(day_embed, episode_ctx, n_episodes,
                                           W_pool, b_pool, x_T);
    dim3 gB(32, 8);
    mlp1_kernel<<<gB, 256, 0, stream>>>(x_T, W1, part);

    tail_kernel<<<64, 256, 0, stream>>>(part, b1, W2, b2, out);
}